// Round 2
// baseline (2369.826 us; speedup 1.0000x reference)
//
#include <hip/hip_runtime.h>
#include <math.h>

#define TL 128        // text length (m)
#define IL 100        // image length (n)
#define ILP 104       // n padded to multiple of 4
#define DIM 768
#define NSEQ 228
#define KT 32         // K tile
#define XLD 132       // LDS leading dim for X tile (128+4 pad)
#define YLD 104       // LDS leading dim for Y tile
#define NTHREADS 832  // 13 waves; thread grid 32 (m-groups) x 26 (n-groups)
#define NWAVES 13
#define ITERS 50

typedef float v2f __attribute__((ext_vector_type(2)));

// launch_bounds(832, 2): min-waves-per-EU=2 is satisfiable by ONE resident
// 13-wave block (EUs get 4/3/3/3 waves) -> VGPR cap 256, no spill.
// Round-1 lesson: (832, 4) forced the compiler to assume 2 blocks/CU ->
// 64-VGPR cap -> qq/aa/cc spilled to scratch -> 6 GB HBM traffic, 1.9 ms.
__global__ void __launch_bounds__(NTHREADS, 2)
WRA_ot_kernel(const float* __restrict__ seq,
              const int* __restrict__ txt_pad,
              const int* __restrict__ img_pad,
              const int* __restrict__ is_correct,
              float* __restrict__ out, int nblocks)
{
    __shared__ __align__(16) float Xt[KT * XLD];
    __shared__ __align__(16) float Yt[KT * YLD];
    __shared__ __align__(16) float xm[TL];    // txt pad mask * 1e4
    __shared__ __align__(16) float ym[ILP];   // img pad mask * 1e4 (pad rows -> 1e4)
    __shared__ __align__(16) float inx[TL];   // sum sq -> inv norm (text)
    __shared__ __align__(16) float iny[ILP];  // sum sq -> inv norm (img)
    __shared__ __align__(16) float sig[TL];   // sigma
    __shared__ __align__(16) float wp[NWAVES * TL]; // per-wave partials for s[m]
    __shared__ float red[NWAVES];
    __shared__ int cnt[2];

    const int t  = threadIdx.x;
    const int b  = blockIdx.x;
    const int mg = t & 31;   // m-group: m in [4mg, 4mg+4)
    const int ng = t >> 5;   // n-group: n in [4ng, 4ng+4), 0..25 (24.. partially fake)
    const int wv = t >> 6;   // wave id 0..12

    // ---- masks & lengths ----
    if (t < 2) cnt[t] = 0;
    __syncthreads();
    if (t < TL) {
        int p = txt_pad[b * TL + t] ? 1 : 0;
        xm[t] = p ? 1e4f : 0.0f;
        if (p) atomicAdd(&cnt[0], 1);
    } else if (t < TL + IL) {
        int p = img_pad[b * IL + (t - TL)] ? 1 : 0;
        ym[t - TL] = p ? 1e4f : 0.0f;
        if (p) atomicAdd(&cnt[1], 1);
    } else if (t < TL + ILP) {
        ym[t - TL] = 1e4f;   // fake rows n=100..103
    }

    // ---- GEMM phase: D[m,n] = sum_k X[m,k] Y[n,k]; norms accumulated inline ----
    const float* Xg = seq + (size_t)b * NSEQ * DIM;       // text rows 0..127
    const float* Yg = Xg + (size_t)TL * DIM;              // img rows 0..99

    v2f acc[4][4];   // [j = n idx][i = m idx]
    v2f sx2[4], sy2[4];
#pragma unroll
    for (int j = 0; j < 4; j++) {
        sx2[j].x = 0.f; sx2[j].y = 0.f;
        sy2[j].x = 0.f; sy2[j].y = 0.f;
#pragma unroll
        for (int i = 0; i < 4; i++) { acc[j][i].x = 0.f; acc[j][i].y = 0.f; }
    }
    const bool do_sx = (ng == 0);
    const bool do_sy = (mg == 0);

    for (int kt0 = 0; kt0 < DIM; kt0 += KT) {
        __syncthreads();
        for (int f = t; f < (TL * KT / 4); f += NTHREADS) {   // 1024 float4
            int row = f >> 3, kc = (f & 7) << 2;
            float4 v = *(const float4*)(Xg + row * DIM + kt0 + kc);
            Xt[(kc + 0) * XLD + row] = v.x;
            Xt[(kc + 1) * XLD + row] = v.y;
            Xt[(kc + 2) * XLD + row] = v.z;
            Xt[(kc + 3) * XLD + row] = v.w;
        }
        for (int f = t; f < (IL * KT / 4); f += NTHREADS) {   // 800 float4
            int row = f >> 3, kc = (f & 7) << 2;
            float4 v = *(const float4*)(Yg + row * DIM + kt0 + kc);
            Yt[(kc + 0) * YLD + row] = v.x;
            Yt[(kc + 1) * YLD + row] = v.y;
            Yt[(kc + 2) * YLD + row] = v.z;
            Yt[(kc + 3) * YLD + row] = v.w;
        }
        __syncthreads();
#pragma unroll
        for (int kk = 0; kk < KT; kk += 2) {
            float4 xa = *(const float4*)&Xt[kk * XLD + 4 * mg];
            float4 xb = *(const float4*)&Xt[(kk + 1) * XLD + 4 * mg];
            float4 ya = *(const float4*)&Yt[kk * YLD + 4 * ng];
            float4 yb = *(const float4*)&Yt[(kk + 1) * YLD + 4 * ng];
            v2f px[4] = { {xa.x, xb.x}, {xa.y, xb.y}, {xa.z, xb.z}, {xa.w, xb.w} };
            v2f py[4] = { {ya.x, yb.x}, {ya.y, yb.y}, {ya.z, yb.z}, {ya.w, yb.w} };
#pragma unroll
            for (int j = 0; j < 4; j++)
#pragma unroll
                for (int i = 0; i < 4; i++)
                    acc[j][i] += px[i] * py[j];
            if (do_sx) {
#pragma unroll
                for (int i = 0; i < 4; i++) sx2[i] += px[i] * px[i];
            }
            if (do_sy) {
#pragma unroll
                for (int j = 0; j < 4; j++) sy2[j] += py[j] * py[j];
            }
        }
    }

    if (do_sx) {
#pragma unroll
        for (int i = 0; i < 4; i++) inx[4 * mg + i] = sx2[i].x + sx2[i].y;
    }
    if (do_sy) {
#pragma unroll
        for (int j = 0; j < 4; j++) iny[4 * ng + j] = sy2[j].x + sy2[j].y;
    }
    __syncthreads();
    if (t < TL) {
        inx[t] = 1.0f / fmaxf(sqrtf(inx[t]), 1e-5f);
    } else if (t < TL + ILP) {
        iny[t - TL] = 1.0f / fmaxf(sqrtf(iny[t - TL]), 1e-5f);
    }
    __syncthreads();

    const float xlen = (float)(TL - cnt[0]);
    const float ylen = (float)(IL - cnt[1]);

    float4 f4;
    float rx[4], ry[4], xmv[4], ymv[4];
    f4 = *(const float4*)&inx[4 * mg]; rx[0]=f4.x; rx[1]=f4.y; rx[2]=f4.z; rx[3]=f4.w;
    f4 = *(const float4*)&iny[4 * ng]; ry[0]=f4.x; ry[1]=f4.y; ry[2]=f4.z; ry[3]=f4.w;
    f4 = *(const float4*)&xm[4 * mg];  xmv[0]=f4.x; xmv[1]=f4.y; xmv[2]=f4.z; xmv[3]=f4.w;
    f4 = *(const float4*)&ym[4 * ng];  ymv[0]=f4.x; ymv[1]=f4.y; ymv[2]=f4.z; ymv[3]=f4.w;

    // cc = masked cost, aa = masked exp(-2C), qq = running Q (Q_1 = A)
    float cc[4][4], aa[4][4], qq[4][4];
#pragma unroll
    for (int j = 0; j < 4; j++)
#pragma unroll
        for (int i = 0; i < 4; i++) {
            float d = acc[j][i].x + acc[j][i].y;
            bool pad = (xmv[i] > 0.0f) || (ymv[j] > 0.0f);
            float c = pad ? 0.0f : (1.0f - d * rx[i] * ry[j]);
            float a = pad ? 0.0f : expf(-2.0f * c);
            cc[j][i] = c; aa[j][i] = a; qq[j][i] = a;
        }

    // sigma_0
    if (t < TL) sig[t] = (xm[t] > 0.0f) ? 0.0f : (1.0f / xlen);
    __syncthreads();

    float ss[4];
    f4 = *(const float4*)&sig[4 * mg]; ss[0]=f4.x; ss[1]=f4.y; ss[2]=f4.z; ss[3]=f4.w;

    float dl[4];
    for (int it = 0; it < ITERS; ++it) {
        // qs[n] = sum_m Q sigma ; butterfly over the 32 m-groups (contiguous half-wave)
#pragma unroll
        for (int j = 0; j < 4; j++) {
            float p = qq[j][0]*ss[0] + qq[j][1]*ss[1] + qq[j][2]*ss[2] + qq[j][3]*ss[3];
            p += __shfl_xor(p, 1);
            p += __shfl_xor(p, 2);
            p += __shfl_xor(p, 4);
            p += __shfl_xor(p, 8);
            p += __shfl_xor(p, 16);
            dl[j] = __builtin_amdgcn_rcpf(ylen * p + ymv[j]);
        }
        // s[m] = sum_n delta Q : in-thread (4 n) + cross-half (xor 32) + 13-wave LDS combine
        float sp[4];
#pragma unroll
        for (int i = 0; i < 4; i++) {
            float s = dl[0]*qq[0][i] + dl[1]*qq[1][i] + dl[2]*qq[2][i] + dl[3]*qq[3][i];
            s += __shfl_xor(s, 32);
            sp[i] = s;
        }
        if ((t & 63) < 32) {
            *(float4*)&wp[wv * TL + 4 * mg] = make_float4(sp[0], sp[1], sp[2], sp[3]);
        }
        __syncthreads();
        if (t < TL) {
            float s = 0.0f;
#pragma unroll
            for (int w = 0; w < NWAVES; w++) s += wp[w * TL + t];
            sig[t] = __builtin_amdgcn_rcpf(xlen * s + xm[t]);
        }
        __syncthreads();
        f4 = *(const float4*)&sig[4 * mg]; ss[0]=f4.x; ss[1]=f4.y; ss[2]=f4.z; ss[3]=f4.w;
        if (it < ITERS - 1) {
#pragma unroll
            for (int j = 0; j < 4; j++) {
                float dj = dl[j];
#pragma unroll
                for (int i = 0; i < 4; i++)
                    qq[j][i] = (qq[j][i] * aa[j][i]) * (dj * ss[i]);
            }
        }
    }

    // ot = sum C^T (.) T_50, T_50 = delta (x) Q_50 (.) sigma
    float local = 0.0f;
#pragma unroll
    for (int j = 0; j < 4; j++)
#pragma unroll
        for (int i = 0; i < 4; i++)
            local += cc[j][i] * qq[j][i] * (dl[j] * ss[i]);

    local += __shfl_xor(local, 1);
    local += __shfl_xor(local, 2);
    local += __shfl_xor(local, 4);
    local += __shfl_xor(local, 8);
    local += __shfl_xor(local, 16);
    local += __shfl_xor(local, 32);
    if ((t & 63) == 0) red[wv] = local;
    __syncthreads();
    if (t == 0) {
        float tot = 0.0f;
#pragma unroll
        for (int w = 0; w < NWAVES; w++) tot += red[w];
        float sgn = (is_correct[b] == 1) ? 1.0f : -1.0f;
        atomicAdd(out, sgn * tot / (float)nblocks);
    }
}

extern "C" void kernel_launch(void* const* d_in, const int* in_sizes, int n_in,
                              void* d_out, int out_size, void* d_ws, size_t ws_size,
                              hipStream_t stream) {
    const float* seq     = (const float*)d_in[0];
    // d_in[1] = input_ids (unused), d_in[2] = image_feat (unused by reference math)
    const int* txt_pad   = (const int*)d_in[3];
    const int* img_pad   = (const int*)d_in[4];
    const int* is_corr   = (const int*)d_in[5];
    float* out = (float*)d_out;
    const int B = in_sizes[5];

    hipMemsetAsync(out, 0, sizeof(float), stream);
    WRA_ot_kernel<<<B, NTHREADS, 0, stream>>>(seq, txt_pad, img_pad, is_corr, out, B);
}

// Round 3
// 2123.832 us; speedup vs baseline: 1.1158x; 1.1158x over previous
//
#include <hip/hip_runtime.h>
#include <math.h>

#define TL 128        // text length (m)
#define IL 100        // image length (n)
#define ILP 104       // n padded to multiple of 4
#define DIM 768
#define NSEQ 228
#define KT 32         // K tile
#define XLD 132       // LDS leading dim for X tile (128+4 pad)
#define YLD 104       // LDS leading dim for Y tile
#define NTHREADS 832  // 13 waves; thread grid 32 (m-groups) x 26 (n-groups)
#define NWAVES 13
#define ITERS 50

typedef float v2f __attribute__((ext_vector_type(2)));

// Round-2 lesson: __launch_bounds__(832, {4,2}) BOTH produced a 64-VGPR cap
// (second arg behaves like CUDA min-blocks: 2 blocks x 13 waves -> 7 waves/EU
// -> 512/7 -> 64-granule) -> qq/aa/cc spilled -> ~6 GB scratch HBM traffic.
// Fix: set LLVM attrs directly. waves_per_eu min=2 -> VGPR budget 512/2=256.
__global__ void
__attribute__((amdgpu_flat_work_group_size(832, 832), amdgpu_waves_per_eu(2, 8)))
WRA_ot_kernel(const float* __restrict__ seq,
              const int* __restrict__ txt_pad,
              const int* __restrict__ img_pad,
              const int* __restrict__ is_correct,
              float* __restrict__ out, int nblocks)
{
    __shared__ __align__(16) float Xt[KT * XLD];
    __shared__ __align__(16) float Yt[KT * YLD];
    __shared__ __align__(16) float xm[TL];    // txt pad mask * 1e4
    __shared__ __align__(16) float ym[ILP];   // img pad mask * 1e4 (pad rows -> 1e4)
    __shared__ __align__(16) float inx[TL];   // sum sq -> inv norm (text)
    __shared__ __align__(16) float iny[ILP];  // sum sq -> inv norm (img)
    __shared__ __align__(16) float sig[TL];   // sigma
    __shared__ __align__(16) float wp[NWAVES * TL]; // per-wave partials for s[m]
    __shared__ float red[NWAVES];
    __shared__ int cnt[2];

    const int t  = threadIdx.x;
    const int b  = blockIdx.x;
    const int mg = t & 31;   // m-group: m in [4mg, 4mg+4)
    const int ng = t >> 5;   // n-group: n in [4ng, 4ng+4), 0..25 (n>=100 fake)
    const int wv = t >> 6;   // wave id 0..12

    // ---- masks & lengths ----
    if (t < 2) cnt[t] = 0;
    __syncthreads();
    if (t < TL) {
        int p = txt_pad[b * TL + t] ? 1 : 0;
        xm[t] = p ? 1e4f : 0.0f;
        if (p) atomicAdd(&cnt[0], 1);
    } else if (t < TL + IL) {
        int p = img_pad[b * IL + (t - TL)] ? 1 : 0;
        ym[t - TL] = p ? 1e4f : 0.0f;
        if (p) atomicAdd(&cnt[1], 1);
    } else if (t < TL + ILP) {
        ym[t - TL] = 1e4f;   // fake rows n=100..103
    }

    // ---- GEMM phase: D[m,n] = sum_k X[m,k] Y[n,k]; norms accumulated inline ----
    const float* Xg = seq + (size_t)b * NSEQ * DIM;       // text rows 0..127
    const float* Yg = Xg + (size_t)TL * DIM;              // img rows 0..99

    v2f acc[4][4];   // [j = n idx][i = m idx]
    v2f sx2[4], sy2[4];
#pragma unroll
    for (int j = 0; j < 4; j++) {
        sx2[j].x = 0.f; sx2[j].y = 0.f;
        sy2[j].x = 0.f; sy2[j].y = 0.f;
#pragma unroll
        for (int i = 0; i < 4; i++) { acc[j][i].x = 0.f; acc[j][i].y = 0.f; }
    }
    const bool do_sx = (ng == 0);
    const bool do_sy = (mg == 0);

    for (int kt0 = 0; kt0 < DIM; kt0 += KT) {
        __syncthreads();
        for (int f = t; f < (TL * KT / 4); f += NTHREADS) {   // 1024 float4
            int row = f >> 3, kc = (f & 7) << 2;
            float4 v = *(const float4*)(Xg + row * DIM + kt0 + kc);
            Xt[(kc + 0) * XLD + row] = v.x;
            Xt[(kc + 1) * XLD + row] = v.y;
            Xt[(kc + 2) * XLD + row] = v.z;
            Xt[(kc + 3) * XLD + row] = v.w;
        }
        for (int f = t; f < (IL * KT / 4); f += NTHREADS) {   // 800 float4
            int row = f >> 3, kc = (f & 7) << 2;
            float4 v = *(const float4*)(Yg + row * DIM + kt0 + kc);
            Yt[(kc + 0) * YLD + row] = v.x;
            Yt[(kc + 1) * YLD + row] = v.y;
            Yt[(kc + 2) * YLD + row] = v.z;
            Yt[(kc + 3) * YLD + row] = v.w;
        }
        __syncthreads();
#pragma unroll
        for (int kk = 0; kk < KT; kk += 2) {
            float4 xa = *(const float4*)&Xt[kk * XLD + 4 * mg];
            float4 xb = *(const float4*)&Xt[(kk + 1) * XLD + 4 * mg];
            float4 ya = *(const float4*)&Yt[kk * YLD + 4 * ng];
            float4 yb = *(const float4*)&Yt[(kk + 1) * YLD + 4 * ng];
            v2f px[4] = { {xa.x, xb.x}, {xa.y, xb.y}, {xa.z, xb.z}, {xa.w, xb.w} };
            v2f py[4] = { {ya.x, yb.x}, {ya.y, yb.y}, {ya.z, yb.z}, {ya.w, yb.w} };
#pragma unroll
            for (int j = 0; j < 4; j++)
#pragma unroll
                for (int i = 0; i < 4; i++)
                    acc[j][i] += px[i] * py[j];
            if (do_sx) {
#pragma unroll
                for (int i = 0; i < 4; i++) sx2[i] += px[i] * px[i];
            }
            if (do_sy) {
#pragma unroll
                for (int j = 0; j < 4; j++) sy2[j] += py[j] * py[j];
            }
        }
    }

    if (do_sx) {
#pragma unroll
        for (int i = 0; i < 4; i++) inx[4 * mg + i] = sx2[i].x + sx2[i].y;
    }
    if (do_sy) {
#pragma unroll
        for (int j = 0; j < 4; j++) iny[4 * ng + j] = sy2[j].x + sy2[j].y;
    }
    __syncthreads();
    if (t < TL) {
        inx[t] = 1.0f / fmaxf(sqrtf(inx[t]), 1e-5f);
    } else if (t < TL + ILP) {
        iny[t - TL] = 1.0f / fmaxf(sqrtf(iny[t - TL]), 1e-5f);
    }
    __syncthreads();

    const float xlen = (float)(TL - cnt[0]);
    const float ylen = (float)(IL - cnt[1]);

    float4 f4;
    float rx[4], ry[4], xmv[4], ymv[4];
    f4 = *(const float4*)&inx[4 * mg]; rx[0]=f4.x; rx[1]=f4.y; rx[2]=f4.z; rx[3]=f4.w;
    f4 = *(const float4*)&iny[4 * ng]; ry[0]=f4.x; ry[1]=f4.y; ry[2]=f4.z; ry[3]=f4.w;
    f4 = *(const float4*)&xm[4 * mg];  xmv[0]=f4.x; xmv[1]=f4.y; xmv[2]=f4.z; xmv[3]=f4.w;
    f4 = *(const float4*)&ym[4 * ng];  ymv[0]=f4.x; ymv[1]=f4.y; ymv[2]=f4.z; ymv[3]=f4.w;

    // aa = masked exp(-2C) (C recovered as -0.5*ln(aa) in epilogue), qq = running Q
    float aa[4][4], qq[4][4];
#pragma unroll
    for (int j = 0; j < 4; j++)
#pragma unroll
        for (int i = 0; i < 4; i++) {
            float d = acc[j][i].x + acc[j][i].y;
            bool pad = (xmv[i] > 0.0f) || (ymv[j] > 0.0f);
            float c = pad ? 0.0f : (1.0f - d * rx[i] * ry[j]);
            float a = pad ? 0.0f : expf(-2.0f * c);
            aa[j][i] = a; qq[j][i] = a;
        }

    // sigma_0
    if (t < TL) sig[t] = (xm[t] > 0.0f) ? 0.0f : (1.0f / xlen);
    __syncthreads();

    float ss[4];
    f4 = *(const float4*)&sig[4 * mg]; ss[0]=f4.x; ss[1]=f4.y; ss[2]=f4.z; ss[3]=f4.w;

    float dl[4];
    for (int it = 0; it < ITERS; ++it) {
        // qs[n] = sum_m Q sigma ; butterfly over the 32 m-groups (contiguous half-wave)
#pragma unroll
        for (int j = 0; j < 4; j++) {
            float p = qq[j][0]*ss[0] + qq[j][1]*ss[1] + qq[j][2]*ss[2] + qq[j][3]*ss[3];
            p += __shfl_xor(p, 1);
            p += __shfl_xor(p, 2);
            p += __shfl_xor(p, 4);
            p += __shfl_xor(p, 8);
            p += __shfl_xor(p, 16);
            dl[j] = __builtin_amdgcn_rcpf(ylen * p + ymv[j]);
        }
        // s[m] = sum_n delta Q : in-thread (4 n) + cross-half (xor 32) + 13-wave LDS combine
        float sp[4];
#pragma unroll
        for (int i = 0; i < 4; i++) {
            float s = dl[0]*qq[0][i] + dl[1]*qq[1][i] + dl[2]*qq[2][i] + dl[3]*qq[3][i];
            s += __shfl_xor(s, 32);
            sp[i] = s;
        }
        if ((t & 63) < 32) {
            *(float4*)&wp[wv * TL + 4 * mg] = make_float4(sp[0], sp[1], sp[2], sp[3]);
        }
        __syncthreads();
        if (t < TL) {
            float s = 0.0f;
#pragma unroll
            for (int w = 0; w < NWAVES; w++) s += wp[w * TL + t];
            sig[t] = __builtin_amdgcn_rcpf(xlen * s + xm[t]);
        }
        __syncthreads();
        f4 = *(const float4*)&sig[4 * mg]; ss[0]=f4.x; ss[1]=f4.y; ss[2]=f4.z; ss[3]=f4.w;
        if (it < ITERS - 1) {
#pragma unroll
            for (int j = 0; j < 4; j++) {
                float dj = dl[j];
#pragma unroll
                for (int i = 0; i < 4; i++)
                    qq[j][i] = (qq[j][i] * aa[j][i]) * (dj * ss[i]);
            }
        }
    }

    // ot = sum C^T (.) T_50, T_50 = delta (x) Q_50 (.) sigma
    // C recovered from aa: a=exp(-2c) -> c=-0.5*ln(a); pad lanes have qq=0 anyway.
    float local = 0.0f;
#pragma unroll
    for (int j = 0; j < 4; j++)
#pragma unroll
        for (int i = 0; i < 4; i++) {
            float a = aa[j][i];
            float c = (a > 0.0f) ? (-0.5f * logf(a)) : 0.0f;
            local += c * qq[j][i] * (dl[j] * ss[i]);
        }

    local += __shfl_xor(local, 1);
    local += __shfl_xor(local, 2);
    local += __shfl_xor(local, 4);
    local += __shfl_xor(local, 8);
    local += __shfl_xor(local, 16);
    local += __shfl_xor(local, 32);
    if ((t & 63) == 0) red[wv] = local;
    __syncthreads();
    if (t == 0) {
        float tot = 0.0f;
#pragma unroll
        for (int w = 0; w < NWAVES; w++) tot += red[w];
        float sgn = (is_correct[b] == 1) ? 1.0f : -1.0f;
        atomicAdd(out, sgn * tot / (float)nblocks);
    }
}

extern "C" void kernel_launch(void* const* d_in, const int* in_sizes, int n_in,
                              void* d_out, int out_size, void* d_ws, size_t ws_size,
                              hipStream_t stream) {
    const float* seq     = (const float*)d_in[0];
    // d_in[1] = input_ids (unused), d_in[2] = image_feat (unused by reference math)
    const int* txt_pad   = (const int*)d_in[3];
    const int* img_pad   = (const int*)d_in[4];
    const int* is_corr   = (const int*)d_in[5];
    float* out = (float*)d_out;
    const int B = in_sizes[5];

    hipMemsetAsync(out, 0, sizeof(float), stream);
    WRA_ot_kernel<<<B, NTHREADS, 0, stream>>>(seq, txt_pad, img_pad, is_corr, out, B);
}

// Round 4
// 441.568 us; speedup vs baseline: 5.3668x; 4.8097x over previous
//
#include <hip/hip_runtime.h>
#include <math.h>

#define TL 128        // text length (m)
#define IL 100        // image length (n)
#define ILP 104       // n padded to multiple of 4
#define DIM 768
#define NSEQ 228
#define KT 32         // K tile
#define XLD 132       // LDS leading dim for X tile (transposed, +4 pad)
#define YLD 104       // LDS leading dim for Y tile
#define NTHREADS 832  // 13 waves; thread grid 32 (m-groups) x 26 (n-groups)
#define NWAVES 13
#define ITERS 50

typedef float v2f __attribute__((ext_vector_type(2)));

// Rounds 1-3 lesson: this 13-wave kernel gets a hard 64-VGPR cap no matter
// what launch_bounds / amdgpu_waves_per_eu says -> any design with >64 live
// VGPRs spills ~6 GB to scratch. This version is designed to FIT 64:
//  - A matrix lives in LDS (thread-private layout As[j][tid][i], float4
//    aligned, conflict-free, no barriers), only qq[16] persists in regs.
//  - row sum-squares accumulated during staging (3 private scalars + one-time
//    LDS atomics) instead of inside the FMA loop.
//  - cc recovered as -0.5*ln(aa) in the epilogue.
__global__ void
__attribute__((amdgpu_flat_work_group_size(NTHREADS, NTHREADS), amdgpu_waves_per_eu(2, 8)))
WRA_ot_kernel(const float* __restrict__ seq,
              const int* __restrict__ txt_pad,
              const int* __restrict__ img_pad,
              const int* __restrict__ is_correct,
              float* __restrict__ out, int nblocks)
{
    // GEMM tiles (dead after k-loop) share space with the A matrix (live after).
    __shared__ __align__(16) union {
        struct { float Xt[KT * XLD]; float Yt[KT * YLD]; } g;   // 30208 B
        float As[4 * NTHREADS * 4];                              // 53248 B
    } u;
    __shared__ __align__(16) float sums[NSEQ];  // per-row sum of squares
    __shared__ __align__(16) float xm[TL];      // txt pad mask * 1e4
    __shared__ __align__(16) float ym[ILP];     // img pad mask * 1e4 (fake rows -> 1e4)
    __shared__ __align__(16) float inx[TL];     // inv norm (text)
    __shared__ __align__(16) float iny[ILP];    // inv norm (img)
    __shared__ __align__(16) float sig[TL];     // sigma
    __shared__ __align__(16) float wp[NWAVES * TL]; // per-wave partials for s[m]
    __shared__ float red[NWAVES];
    __shared__ int cnt[2];
    // total LDS: 53248+912+512+416+512+416+512+6656+52+8 = 63244 B < 64 KB

    const int t  = threadIdx.x;
    const int b  = blockIdx.x;
    const int mg = t & 31;   // m-group: m in [4mg, 4mg+4)
    const int ng = t >> 5;   // n-group: n in [4ng, 4ng+4), ng=25 rows are fake
    const int wv = t >> 6;   // wave id 0..12

    // ---- phase 0: masks, lengths, zero sums ----
    if (t < 2) cnt[t] = 0;
    if (t < NSEQ) sums[t] = 0.0f;
    __syncthreads();
    if (t < TL) {
        int p = txt_pad[b * TL + t] ? 1 : 0;
        xm[t] = p ? 1e4f : 0.0f;
        if (p) atomicAdd(&cnt[0], 1);
    } else if (t < TL + IL) {
        int p = img_pad[b * IL + (t - TL)] ? 1 : 0;
        ym[t - TL] = p ? 1e4f : 0.0f;
        if (p) atomicAdd(&cnt[1], 1);
    } else if (t < TL + ILP) {
        ym[t - TL] = 1e4f;   // fake rows n=100..103
    }

    // ---- phase 1: GEMM  D[m,n] = sum_k X[m,k] Y[n,k] ----
    const float* Xg = seq + (size_t)b * NSEQ * DIM;   // text rows 0..127
    const float* Yg = Xg + (size_t)TL * DIM;          // img rows 0..99

    v2f acc[4][4];   // [j = n idx][i = m idx]
#pragma unroll
    for (int j = 0; j < 4; j++)
#pragma unroll
        for (int i = 0; i < 4; i++) { acc[j][i].x = 0.f; acc[j][i].y = 0.f; }

    // staging-time norm accumulators: each thread stages fixed rows
    float nrm0 = 0.0f, nrm1 = 0.0f, nrm2 = 0.0f;
    const int xrow0 = t >> 3;                 // X chunk 1 row (f = t)
    const int xrow1 = (t + NTHREADS) >> 3;    // X chunk 2 row (f = t+832), t<192
    const int yrow  = t >> 3;                 // Y row (f = t), t<800

    for (int kt0 = 0; kt0 < DIM; kt0 += KT) {
        __syncthreads();
        {   // X tile: 1024 float4, transposed into Xt[k][m]
            int kc = (t & 7) << 2;
            float4 v = *(const float4*)(Xg + xrow0 * DIM + kt0 + kc);
            u.g.Xt[(kc + 0) * XLD + xrow0] = v.x;
            u.g.Xt[(kc + 1) * XLD + xrow0] = v.y;
            u.g.Xt[(kc + 2) * XLD + xrow0] = v.z;
            u.g.Xt[(kc + 3) * XLD + xrow0] = v.w;
            nrm0 += v.x * v.x + v.y * v.y + v.z * v.z + v.w * v.w;
            if (t < 1024 - NTHREADS) {
                int f = t + NTHREADS;
                int kc2 = (f & 7) << 2;
                float4 w = *(const float4*)(Xg + xrow1 * DIM + kt0 + kc2);
                u.g.Xt[(kc2 + 0) * XLD + xrow1] = w.x;
                u.g.Xt[(kc2 + 1) * XLD + xrow1] = w.y;
                u.g.Xt[(kc2 + 2) * XLD + xrow1] = w.z;
                u.g.Xt[(kc2 + 3) * XLD + xrow1] = w.w;
                nrm1 += w.x * w.x + w.y * w.y + w.z * w.z + w.w * w.w;
            }
        }
        if (t < 800) {  // Y tile: 800 float4, transposed into Yt[k][n]
            int kc = (t & 7) << 2;
            float4 v = *(const float4*)(Yg + yrow * DIM + kt0 + kc);
            u.g.Yt[(kc + 0) * YLD + yrow] = v.x;
            u.g.Yt[(kc + 1) * YLD + yrow] = v.y;
            u.g.Yt[(kc + 2) * YLD + yrow] = v.z;
            u.g.Yt[(kc + 3) * YLD + yrow] = v.w;
            nrm2 += v.x * v.x + v.y * v.y + v.z * v.z + v.w * v.w;
        }
        __syncthreads();
#pragma unroll
        for (int kk = 0; kk < KT; kk += 2) {
            float4 xa = *(const float4*)&u.g.Xt[kk * XLD + 4 * mg];
            float4 xb = *(const float4*)&u.g.Xt[(kk + 1) * XLD + 4 * mg];
            float4 ya = *(const float4*)&u.g.Yt[kk * YLD + 4 * ng];
            float4 yb = *(const float4*)&u.g.Yt[(kk + 1) * YLD + 4 * ng];
            v2f px[4] = { {xa.x, xb.x}, {xa.y, xb.y}, {xa.z, xb.z}, {xa.w, xb.w} };
            v2f py[4] = { {ya.x, yb.x}, {ya.y, yb.y}, {ya.z, yb.z}, {ya.w, yb.w} };
#pragma unroll
            for (int j = 0; j < 4; j++)
#pragma unroll
                for (int i = 0; i < 4; i++)
                    acc[j][i] += px[i] * py[j];
        }
    }

    // fold per-thread norm partials into per-row sums (one-time)
    atomicAdd(&sums[xrow0], nrm0);
    if (t < 1024 - NTHREADS) atomicAdd(&sums[xrow1], nrm1);
    if (t < 800) atomicAdd(&sums[TL + yrow], nrm2);
    __syncthreads();   // also fences last use of Xt/Yt before As overwrite

    if (t < TL) {
        inx[t] = 1.0f / fmaxf(sqrtf(sums[t]), 1e-5f);
    } else if (t < TL + IL) {
        iny[t - TL] = 1.0f / fmaxf(sqrtf(sums[t]), 1e-5f);
    } else if (t < TL + ILP) {
        iny[t - TL] = 1.0f;   // fake rows: any finite value (a forced to 0)
    }
    __syncthreads();

    const float xlen = (float)(TL - cnt[0]);
    const float ylen = (float)(IL - cnt[1]);

    float4 f4;
    float rx[4], ry[4], ymv[4];
    f4 = *(const float4*)&inx[4 * mg]; rx[0]=f4.x; rx[1]=f4.y; rx[2]=f4.z; rx[3]=f4.w;
    f4 = *(const float4*)&iny[4 * ng]; ry[0]=f4.x; ry[1]=f4.y; ry[2]=f4.z; ry[3]=f4.w;
    f4 = *(const float4*)&ym[4 * ng];  ymv[0]=f4.x; ymv[1]=f4.y; ymv[2]=f4.z; ymv[3]=f4.w;
    float xmv0, xmv1, xmv2, xmv3;
    f4 = *(const float4*)&xm[4 * mg];  xmv0=f4.x; xmv1=f4.y; xmv2=f4.z; xmv3=f4.w;

    // epilogue: a = masked exp(-2C) -> LDS (thread-private float4 slots) + qq regs
    float qq[4][4];
#pragma unroll
    for (int j = 0; j < 4; j++) {
        float4 av;
        float xv[4] = {xmv0, xmv1, xmv2, xmv3};
#pragma unroll
        for (int i = 0; i < 4; i++) {
            float d = acc[j][i].x + acc[j][i].y;
            bool pad = (xv[i] > 0.0f) || (ymv[j] > 0.0f);
            float c = pad ? 0.0f : (1.0f - d * rx[i] * ry[j]);
            float a = pad ? 0.0f : expf(-2.0f * c);
            ((float*)&av)[i] = a;
            qq[j][i] = a;
        }
        *(float4*)&u.As[(j * NTHREADS + t) * 4] = av;
    }

    // sigma_0
    if (t < TL) sig[t] = (xm[t] > 0.0f) ? 0.0f : (1.0f / xlen);
    __syncthreads();

    float ss[4];
    f4 = *(const float4*)&sig[4 * mg]; ss[0]=f4.x; ss[1]=f4.y; ss[2]=f4.z; ss[3]=f4.w;

    float dl[4];
    for (int it = 0; it < ITERS; ++it) {
        // qs[n] = sum_m Q sigma ; butterfly over 32 m-groups (contiguous half-wave)
#pragma unroll
        for (int j = 0; j < 4; j++) {
            float p = qq[j][0]*ss[0] + qq[j][1]*ss[1] + qq[j][2]*ss[2] + qq[j][3]*ss[3];
            p += __shfl_xor(p, 1);
            p += __shfl_xor(p, 2);
            p += __shfl_xor(p, 4);
            p += __shfl_xor(p, 8);
            p += __shfl_xor(p, 16);
            dl[j] = __builtin_amdgcn_rcpf(ylen * p + ymv[j]);
        }
        // s[m] = sum_n delta Q
        float sp[4];
#pragma unroll
        for (int i = 0; i < 4; i++) {
            float s = dl[0]*qq[0][i] + dl[1]*qq[1][i] + dl[2]*qq[2][i] + dl[3]*qq[3][i];
            s += __shfl_xor(s, 32);
            sp[i] = s;
        }
        if ((t & 63) < 32) {
            *(float4*)&wp[wv * TL + 4 * mg] = make_float4(sp[0], sp[1], sp[2], sp[3]);
        }
        __syncthreads();
        if (t < TL) {
            float s = 0.0f;
#pragma unroll
            for (int w = 0; w < NWAVES; w++) s += wp[w * TL + t];
            sig[t] = __builtin_amdgcn_rcpf(xlen * s + xm[t]);
        }
        __syncthreads();
        f4 = *(const float4*)&sig[4 * mg]; ss[0]=f4.x; ss[1]=f4.y; ss[2]=f4.z; ss[3]=f4.w;
        if (it < ITERS - 1) {
#pragma unroll
            for (int j = 0; j < 4; j++) {
                float4 av = *(const float4*)&u.As[(j * NTHREADS + t) * 4];
                float dj = dl[j];
                qq[j][0] = (qq[j][0] * av.x) * (dj * ss[0]);
                qq[j][1] = (qq[j][1] * av.y) * (dj * ss[1]);
                qq[j][2] = (qq[j][2] * av.z) * (dj * ss[2]);
                qq[j][3] = (qq[j][3] * av.w) * (dj * ss[3]);
            }
        }
    }

    // ot = sum C^T (.) T_50, T_50 = delta (x) Q_50 (.) sigma; c = -0.5*ln(a)
    float local = 0.0f;
#pragma unroll
    for (int j = 0; j < 4; j++) {
        float4 av = *(const float4*)&u.As[(j * NTHREADS + t) * 4];
        float a[4] = {av.x, av.y, av.z, av.w};
#pragma unroll
        for (int i = 0; i < 4; i++) {
            float c = (a[i] > 0.0f) ? (-0.5f * logf(a[i])) : 0.0f;
            local += c * qq[j][i] * (dl[j] * ss[i]);
        }
    }

    local += __shfl_xor(local, 1);
    local += __shfl_xor(local, 2);
    local += __shfl_xor(local, 4);
    local += __shfl_xor(local, 8);
    local += __shfl_xor(local, 16);
    local += __shfl_xor(local, 32);
    if ((t & 63) == 0) red[wv] = local;
    __syncthreads();
    if (t == 0) {
        float tot = 0.0f;
#pragma unroll
        for (int w = 0; w < NWAVES; w++) tot += red[w];
        float sgn = (is_correct[b] == 1) ? 1.0f : -1.0f;
        atomicAdd(out, sgn * tot / (float)nblocks);
    }
}

extern "C" void kernel_launch(void* const* d_in, const int* in_sizes, int n_in,
                              void* d_out, int out_size, void* d_ws, size_t ws_size,
                              hipStream_t stream) {
    const float* seq     = (const float*)d_in[0];
    // d_in[1] = input_ids (unused), d_in[2] = image_feat (unused by reference math)
    const int* txt_pad   = (const int*)d_in[3];
    const int* img_pad   = (const int*)d_in[4];
    const int* is_corr   = (const int*)d_in[5];
    float* out = (float*)d_out;
    const int B = in_sizes[5];

    hipMemsetAsync(out, 0, sizeof(float), stream);
    WRA_ot_kernel<<<B, NTHREADS, 0, stream>>>(seq, txt_pad, img_pad, is_corr, out, B);
}

// Round 5
// 374.449 us; speedup vs baseline: 6.3288x; 1.1793x over previous
//
#include <hip/hip_runtime.h>
#include <math.h>
#include <stdint.h>

#define TL 128        // text length (m)
#define IL 100        // image length (n)
#define NP 112        // n padded for GEMM/As (14 n-tiles of 8)
#define DIM 768
#define NSEQ 228
#define KT 32         // K chunk
#define NT 256        // 4 waves
#define ITERS 50
#define XROW 72       // ushorts per staged row: 32 hi bf16 + 32 lo bf16 + 8 pad

typedef float f32x4 __attribute__((ext_vector_type(4)));
typedef short short8 __attribute__((ext_vector_type(8)));

__device__ __forceinline__ uint16_t f2bf(float x) {
    union { float f; uint32_t u; } v; v.f = x;
    uint32_t r = v.u + 0x7FFFu + ((v.u >> 16) & 1u);   // RNE
    return (uint16_t)(r >> 16);
}
__device__ __forceinline__ float bf2f(uint16_t h) {
    union { float f; uint32_t u; } v; v.u = ((uint32_t)h) << 16;
    return v.f;
}

// Round-4 lesson: 13-wave blocks => hard 64-VGPR cap; both GEMM (4x4 tile,
// 1 B/FLOP LDS) and IPOT (13-wave shfl/barrier structure) were LDS-pipe bound.
// This version: 256 threads, launch_bounds(256,1) => 512-VGPR budget.
// GEMM via split-fp32 (hi+lo bf16) MFMA 16x16x32; IPOT with A and Q fully
// register-resident (8m x 8n per thread), one barrier per iteration.
__global__ void __launch_bounds__(NT, 1)
WRA_ot_kernel(const float* __restrict__ seq,
              const int* __restrict__ txt_pad,
              const int* __restrict__ img_pad,
              const int* __restrict__ is_correct,
              float* __restrict__ out, int nblocks)
{
    __shared__ __align__(16) union {
        struct {
            uint16_t X[TL * XROW];   // 18432 B  (bf16 hi|lo, quad-rotated)
            uint16_t Y[NP * XROW];   // 16128 B
        } g;
        float As[224 * 64];          // 57344 B  raw dot, IPOT-owner layout
    } u;
    __shared__ __align__(16) float sums[NSEQ];   // row sum-squares
    __shared__ __align__(16) float xm[TL];       // txt pad mask * 1e4
    __shared__ __align__(16) float ym[NP];       // img pad mask * 1e4
    __shared__ __align__(16) float inx[TL];      // inv norms
    __shared__ __align__(16) float iny[NP];
    __shared__ __align__(16) float wp[2][4][TL]; // dbuf per-wave s[m] partials
    __shared__ float red[4];
    __shared__ int cnt[2];
    // LDS total: 57344+912+512+448+512+448+4096+16+8 = 64296 B <= 64 KiB

    const int t    = threadIdx.x;
    const int b    = blockIdx.x;
    const int w    = t >> 6;
    const int lane = t & 63;

    // ---- phase 0: masks & lengths ----
    if (t < 2) cnt[t] = 0;
    if (t < NSEQ) sums[t] = 0.0f;
    __syncthreads();
    if (t < TL) {
        int p = txt_pad[b * TL + t] ? 1 : 0;
        xm[t] = p ? 1e4f : 0.0f;
        if (p) atomicAdd(&cnt[0], 1);
    } else if (t < TL + IL) {
        int p = img_pad[b * IL + (t - TL)] ? 1 : 0;
        ym[t - TL] = p ? 1e4f : 0.0f;
        if (p) atomicAdd(&cnt[1], 1);
    } else if (t < TL + NP) {
        ym[t - TL] = 1e4f;   // fake n = 100..111
    }

    // ---- GEMM: raw dot D[m,n] = sum_k X[m,k] Y[n,k] via split-bf16 MFMA ----
    const float* Xg = seq + (size_t)b * NSEQ * DIM;   // text rows 0..127
    const float* Yg = Xg + (size_t)TL * DIM;          // img rows 0..99

    // staging slots: 1824 float4 per chunk, slot f = t + 256*r
    const float* gp[8];
    uint16_t*    dp[8];
    int   srow[8];
    bool  act[8];
    float nrm[8];
    float4 v[8];
#pragma unroll
    for (int r = 0; r < 8; r++) {
        int f = t + NT * r;
        act[r] = (f < 1824);
        nrm[r] = 0.0f;
        int f2 = act[r] ? f : 0;
        bool isX = (f2 < 1024);
        int row = isX ? (f2 >> 3) : ((f2 - 1024) >> 3);
        int kc  = (f2 & 7) << 2;                  // k offset 0..28
        gp[r] = (isX ? Xg : Yg) + row * DIM + kc;
        int nq  = ((kc >> 3) + row) & 3;          // quad rotation (bank swizzle)
        dp[r] = (isX ? u.g.X : u.g.Y) + row * XROW + nq * 8 + (kc & 7);
        srow[r] = isX ? row : (TL + row);
    }
    {   // zero Y pad rows 100..111 once (staging never writes them)
        uint32_t* y32 = (uint32_t*)u.g.Y;
        for (int i = IL * (XROW/2) + t; i < NP * (XROW/2); i += NT) y32[i] = 0;
    }
#pragma unroll
    for (int r = 0; r < 8; r++) if (act[r]) v[r] = *(const float4*)(gp[r]);

    f32x4 acc[2][7];
#pragma unroll
    for (int a = 0; a < 2; a++)
#pragma unroll
        for (int q = 0; q < 7; q++) acc[a][q] = (f32x4){0.f, 0.f, 0.f, 0.f};

    const int lr = lane & 15, lq = lane >> 4;
    for (int c = 0; c < 24; c++) {
        __syncthreads();   // previous chunk's frag reads done (c=0: zero-pad done)
#pragma unroll
        for (int r = 0; r < 8; r++) if (act[r]) {
            float4 x = v[r];
            nrm[r] += x.x*x.x + x.y*x.y + x.z*x.z + x.w*x.w;
            uint16_t h0 = f2bf(x.x), h1 = f2bf(x.y), h2 = f2bf(x.z), h3 = f2bf(x.w);
            uint16_t l0 = f2bf(x.x - bf2f(h0)), l1 = f2bf(x.y - bf2f(h1));
            uint16_t l2 = f2bf(x.z - bf2f(h2)), l3 = f2bf(x.w - bf2f(h3));
            uint64_t hq  = (uint64_t)h0 | ((uint64_t)h1<<16) | ((uint64_t)h2<<32) | ((uint64_t)h3<<48);
            uint64_t lq8 = (uint64_t)l0 | ((uint64_t)l1<<16) | ((uint64_t)l2<<32) | ((uint64_t)l3<<48);
            *(uint64_t*)(dp[r])      = hq;
            *(uint64_t*)(dp[r] + 32) = lq8;
            if (c < 23) v[r] = *(const float4*)(gp[r] + (c + 1) * KT);  // prefetch
        }
        __syncthreads();
        // wave w owns m-tiles {2w, 2w+1} x n-tiles 0..6
        short8 ah[2], al[2], bh[7], bl[7];
#pragma unroll
        for (int a = 0; a < 2; a++) {
            int m = 16 * (2*w + a) + lr;
            int base = m * XROW + 8 * ((lq + m) & 3);
            ah[a] = *(const short8*)&u.g.X[base];
            al[a] = *(const short8*)&u.g.X[base + 32];
        }
#pragma unroll
        for (int q = 0; q < 7; q++) {
            int n = 16 * q + lr;
            int base = n * XROW + 8 * ((lq + n) & 3);
            bh[q] = *(const short8*)&u.g.Y[base];
            bl[q] = *(const short8*)&u.g.Y[base + 32];
        }
#pragma unroll
        for (int a = 0; a < 2; a++)
#pragma unroll
            for (int q = 0; q < 7; q++) {
                acc[a][q] = __builtin_amdgcn_mfma_f32_16x16x32_bf16(ah[a], bh[q], acc[a][q], 0, 0, 0);
                acc[a][q] = __builtin_amdgcn_mfma_f32_16x16x32_bf16(ah[a], bl[q], acc[a][q], 0, 0, 0);
                acc[a][q] = __builtin_amdgcn_mfma_f32_16x16x32_bf16(al[a], bh[q], acc[a][q], 0, 0, 0);
            }
    }

    __syncthreads();   // last frag reads done before As overwrite
#pragma unroll
    for (int r = 0; r < 8; r++) if (act[r]) atomicAdd(&sums[srow[r]], nrm[r]);
    // scatter raw dots into IPOT-owner layout: owner t' = (m>>3) + 16*(n>>3)
#pragma unroll
    for (int a = 0; a < 2; a++)
#pragma unroll
        for (int q = 0; q < 7; q++)
#pragma unroll
            for (int rg = 0; rg < 4; rg++) {
                int m = 16 * (2*w + a) + 4*lq + rg;   // D row = quad*4+reg
                int n = 16 * q + lr;                   // D col = lane&15
                int tp = (m >> 3) + ((n >> 3) << 4);
                u.As[(tp << 6) + ((n & 7) << 3) + (m & 7)] = acc[a][q][rg];
            }
    __syncthreads();
    if (t < TL)            inx[t]      = 1.0f / fmaxf(sqrtf(sums[t]), 1e-5f);
    else if (t < NSEQ)     iny[t - TL] = 1.0f / fmaxf(sqrtf(sums[t]), 1e-5f);
    else if (t < TL + NP)  iny[t - TL] = 1.0f;
    __syncthreads();

    // ---- IPOT: thread (mI, nI) owns m = 8mI..+7, n = 8nI..+7, all in regs ----
    const float xlen = (float)(TL - cnt[0]);
    const float ylen = (float)(IL - cnt[1]);
    const int mI = t & 15, nI = t >> 4;

    float rx[8], xmv[8], ry[8], ymv[8];
    {
        float4 a0 = *(const float4*)&inx[8*mI], a1 = *(const float4*)&inx[8*mI + 4];
        rx[0]=a0.x; rx[1]=a0.y; rx[2]=a0.z; rx[3]=a0.w;
        rx[4]=a1.x; rx[5]=a1.y; rx[6]=a1.z; rx[7]=a1.w;
        float4 b0 = *(const float4*)&xm[8*mI], b1 = *(const float4*)&xm[8*mI + 4];
        xmv[0]=b0.x; xmv[1]=b0.y; xmv[2]=b0.z; xmv[3]=b0.w;
        xmv[4]=b1.x; xmv[5]=b1.y; xmv[6]=b1.z; xmv[7]=b1.w;
        if (nI < 14) {
            float4 c0 = *(const float4*)&iny[8*nI], c1 = *(const float4*)&iny[8*nI + 4];
            ry[0]=c0.x; ry[1]=c0.y; ry[2]=c0.z; ry[3]=c0.w;
            ry[4]=c1.x; ry[5]=c1.y; ry[6]=c1.z; ry[7]=c1.w;
            float4 d0 = *(const float4*)&ym[8*nI], d1 = *(const float4*)&ym[8*nI + 4];
            ymv[0]=d0.x; ymv[1]=d0.y; ymv[2]=d0.z; ymv[3]=d0.w;
            ymv[4]=d1.x; ymv[5]=d1.y; ymv[6]=d1.z; ymv[7]=d1.w;
        } else {
#pragma unroll
            for (int j = 0; j < 8; j++) { ry[j] = 1.0f; ymv[j] = 1e4f; }
        }
    }

    float aa[8][8], qq[8][8];   // [j = n][i = m]
    if (nI < 14) {
#pragma unroll
        for (int j = 0; j < 8; j++) {
            float4 d0 = *(const float4*)&u.As[(t << 6) + (j << 3)];
            float4 d1 = *(const float4*)&u.As[(t << 6) + (j << 3) + 4];
            float dv[8] = {d0.x, d0.y, d0.z, d0.w, d1.x, d1.y, d1.z, d1.w};
#pragma unroll
            for (int i = 0; i < 8; i++) {
                bool pad = (xmv[i] > 0.0f) || (ymv[j] > 0.0f);
                float cc = pad ? 0.0f : (1.0f - dv[i] * rx[i] * ry[j]);
                float av = pad ? 0.0f : expf(-2.0f * cc);
                aa[j][i] = av; qq[j][i] = av;
            }
        }
    } else {
#pragma unroll
        for (int j = 0; j < 8; j++)
#pragma unroll
            for (int i = 0; i < 8; i++) { aa[j][i] = 0.0f; qq[j][i] = 0.0f; }
    }

    float sg[8];
#pragma unroll
    for (int i = 0; i < 8; i++) sg[i] = (xmv[i] > 0.0f) ? 0.0f : (1.0f / xlen);

    float dl[8];
    for (int it = 0; it < ITERS; ++it) {
        // qs[n] = sum_m Q sigma : in-thread 8m, butterfly over 16 mI lanes
        float p[8];
#pragma unroll
        for (int j = 0; j < 8; j++)
            p[j] = qq[j][0]*sg[0] + qq[j][1]*sg[1] + qq[j][2]*sg[2] + qq[j][3]*sg[3]
                 + qq[j][4]*sg[4] + qq[j][5]*sg[5] + qq[j][6]*sg[6] + qq[j][7]*sg[7];
#pragma unroll
        for (int j = 0; j < 8; j++) {
            p[j] += __shfl_xor(p[j], 1);
            p[j] += __shfl_xor(p[j], 2);
            p[j] += __shfl_xor(p[j], 4);
            p[j] += __shfl_xor(p[j], 8);
            dl[j] = __builtin_amdgcn_rcpf(ylen * p[j] + ymv[j]);
        }
        // s[m] = sum_n delta*Q : in-thread 8n, butterfly over in-wave nI, LDS for cross-wave
        float sp[8];
#pragma unroll
        for (int i = 0; i < 8; i++) {
            float s = dl[0]*qq[0][i] + dl[1]*qq[1][i] + dl[2]*qq[2][i] + dl[3]*qq[3][i]
                    + dl[4]*qq[4][i] + dl[5]*qq[5][i] + dl[6]*qq[6][i] + dl[7]*qq[7][i];
            s += __shfl_xor(s, 16);
            s += __shfl_xor(s, 32);
            sp[i] = s;
        }
        if (lane < 16) {
            float* wrow = &wp[it & 1][w][8 * mI];
            *(float4*)wrow       = make_float4(sp[0], sp[1], sp[2], sp[3]);
            *(float4*)(wrow + 4) = make_float4(sp[4], sp[5], sp[6], sp[7]);
        }
        __syncthreads();   // the ONLY barrier per iteration (wp double-buffered)
#pragma unroll
        for (int i = 0; i < 8; i += 4) {
            float4 s0 = *(const float4*)&wp[it & 1][0][8*mI + i];
            float4 s1 = *(const float4*)&wp[it & 1][1][8*mI + i];
            float4 s2 = *(const float4*)&wp[it & 1][2][8*mI + i];
            float4 s3 = *(const float4*)&wp[it & 1][3][8*mI + i];
            sg[i+0] = __builtin_amdgcn_rcpf(xlen*(s0.x+s1.x+s2.x+s3.x) + xmv[i+0]);
            sg[i+1] = __builtin_amdgcn_rcpf(xlen*(s0.y+s1.y+s2.y+s3.y) + xmv[i+1]);
            sg[i+2] = __builtin_amdgcn_rcpf(xlen*(s0.z+s1.z+s2.z+s3.z) + xmv[i+2]);
            sg[i+3] = __builtin_amdgcn_rcpf(xlen*(s0.w+s1.w+s2.w+s3.w) + xmv[i+3]);
        }
        if (it < ITERS - 1) {
#pragma unroll
            for (int j = 0; j < 8; j++) {
                float dj = dl[j];
#pragma unroll
                for (int i = 0; i < 8; i++)
                    qq[j][i] = (qq[j][i] * aa[j][i]) * (dj * sg[i]);
            }
        }
    }

    // ot = sum C^T (.) T_50 ;  c = -0.5*ln(a) on non-pad entries
    float local = 0.0f;
#pragma unroll
    for (int j = 0; j < 8; j++)
#pragma unroll
        for (int i = 0; i < 8; i++) {
            float av = aa[j][i];
            float cc = (av > 0.0f) ? (-0.5f * logf(av)) : 0.0f;
            local += cc * qq[j][i] * (dl[j] * sg[i]);
        }
    local += __shfl_xor(local, 1);
    local += __shfl_xor(local, 2);
    local += __shfl_xor(local, 4);
    local += __shfl_xor(local, 8);
    local += __shfl_xor(local, 16);
    local += __shfl_xor(local, 32);
    if (lane == 0) red[w] = local;
    __syncthreads();
    if (t == 0) {
        float tot = red[0] + red[1] + red[2] + red[3];
        float sgn = (is_correct[b] == 1) ? 1.0f : -1.0f;
        atomicAdd(out, sgn * tot / (float)nblocks);
    }
}

extern "C" void kernel_launch(void* const* d_in, const int* in_sizes, int n_in,
                              void* d_out, int out_size, void* d_ws, size_t ws_size,
                              hipStream_t stream) {
    const float* seq   = (const float*)d_in[0];
    const int* txt_pad = (const int*)d_in[3];
    const int* img_pad = (const int*)d_in[4];
    const int* is_corr = (const int*)d_in[5];
    float* out = (float*)d_out;
    const int B = in_sizes[5];

    hipMemsetAsync(out, 0, sizeof(float), stream);
    WRA_ot_kernel<<<B, NT, 0, stream>>>(seq, txt_pad, img_pad, is_corr, out, B);
}